// Round 3
// baseline (3981.628 us; speedup 1.0000x reference)
//
#include <hip/hip_runtime.h>

#define SS 128
#define DD 768
#define HH 12
#define DHD 64
#define FF 3072
#define VV 50257
#define NCC 29
#define LL 12
#define SD (SS*DD)      // 98304
#define SF (SS*FF)      // 393216
#define TMAX (LL*NCC)   // 348

typedef unsigned short u16;
typedef __attribute__((ext_vector_type(8))) short short8;
typedef __attribute__((ext_vector_type(4))) float f32x4;

__device__ inline u16 f2bf(float f) {
    union { float f; unsigned u; } x; x.f = f;
    unsigned r = x.u + 0x7fffu + ((x.u >> 16) & 1u);
    return (u16)(r >> 16);
}

// ---------------- float mask table: lmf[i][t][j] = rm[i*29+j][t], stride 32
__global__ void k_maskf(const int* __restrict__ rm, float* __restrict__ lmf) {
    int idx = blockIdx.x * 64 + threadIdx.x;
    if (idx >= LL * TMAX) return;
    int i = idx / TMAX, t = idx % TMAX;
    for (int j = 0; j < 26; j++)
        lmf[(size_t)idx * 32 + j] = (float)(rm[(size_t)(i * NCC + j) * TMAX + t] & 1);
}

// ---------------- embedding
__global__ void k_embed(const int* __restrict__ ids, const float* __restrict__ wte,
                        const float* __restrict__ wpe, float* __restrict__ h) {
    int sd = blockIdx.x * 256 + threadIdx.x;
    if (sd >= SD) return;
    int s = sd / DD, d = sd % DD;
    h[sd] = wte[(size_t)ids[s] * DD + d] + wpe[sd];
}

// ---------------- f32 -> bf16 elementwise (wte)
__global__ void k_cvt(const float* __restrict__ in, u16* __restrict__ out, int n4) {
    int i = blockIdx.x * 256 + threadIdx.x;
    if (i >= n4) return;
    float4 v = *(const float4*)(in + (size_t)i * 4);
    u16* o = out + (size_t)i * 4;
    o[0] = f2bf(v.x); o[1] = f2bf(v.y); o[2] = f2bf(v.z); o[3] = f2bf(v.w);
}

// ---------------- qkv bias pack: [L][3*D] -> [L][12 heads][192]
__global__ void k_qkvb(const float* __restrict__ qkv_b, float* __restrict__ qkvbp) {
    int idx = blockIdx.x * 256 + threadIdx.x;
    if (idx >= LL * 3 * DD) return;
    int l = idx / (3 * DD), r = idx % (3 * DD);
    int p = r / DD, rem = r % DD, h = rem / DHD, j = rem % DHD;
    qkvbp[(size_t)l * 3 * DD + h * 192 + p * DHD + j] = qkv_b[idx];
}

// ---------------- weight transpose-convert: W[K][N] f32 -> WT[N][K] bf16
__global__ __launch_bounds__(256) void k_wt(const float* __restrict__ W, u16* __restrict__ WT,
                                            int K, int N, int remap) {
    __shared__ float T[64][65];
    int n0 = blockIdx.x * 64, k0 = blockIdx.y * 64;
    int c = threadIdx.x & 63, r0 = threadIdx.x >> 6;
#pragma unroll
    for (int i = 0; i < 16; i++) {
        int r = r0 + 4 * i;
        T[r][c] = W[(size_t)(k0 + r) * N + n0 + c];
    }
    __syncthreads();
    int ob = n0 >> 6;
    if (remap) { int p = ob / 12, h = ob % 12; ob = h * 3 + p; }
    size_t orow0 = (size_t)ob * 64;
#pragma unroll
    for (int i = 0; i < 16; i++) {
        int a = r0 + 4 * i;
        WT[(orow0 + a) * K + k0 + c] = f2bf(T[c][a]);
    }
}

// ---------------- checks: 26 gated record-sums, 64 sd-lanes x 4 t-stripes per block
__global__ __launch_bounds__(256) void k_check(
    const float* __restrict__ records, const float* __restrict__ lmf,
    const float* __restrict__ h, float* __restrict__ rec0, float* __restrict__ x24,
    float* __restrict__ x3, int layer) {
    __shared__ float red[4][26][64];
    int sd0 = blockIdx.x * 64;
    int lane = threadIdx.x & 63, w = threadIdx.x >> 6;
    int sd = sd0 + lane;
    int T = layer * NCC;
    int T4 = (T + 3) >> 2;
    int tb = w * T4, te = tb + T4; if (te > T) te = T;
    float acc[26];
#pragma unroll
    for (int j = 0; j < 26; j++) acc[j] = 0.f;
    const float* mf = lmf + (size_t)layer * TMAX * 32;
    int t = tb;
    for (; t + 4 <= te; t += 4) {
        float r0 = records[(size_t)(t + 0) * SD + sd];
        float r1 = records[(size_t)(t + 1) * SD + sd];
        float r2 = records[(size_t)(t + 2) * SD + sd];
        float r3 = records[(size_t)(t + 3) * SD + sd];
        const float* m0 = mf + (size_t)(t + 0) * 32;
        const float* m1 = mf + (size_t)(t + 1) * 32;
        const float* m2 = mf + (size_t)(t + 2) * 32;
        const float* m3 = mf + (size_t)(t + 3) * 32;
#pragma unroll
        for (int j = 0; j < 26; j++)
            acc[j] += m0[j] * r0 + m1[j] * r1 + m2[j] * r2 + m3[j] * r3;
    }
    for (; t < te; t++) {
        float r = records[(size_t)t * SD + sd];
        const float* m0 = mf + (size_t)t * 32;
#pragma unroll
        for (int j = 0; j < 26; j++) acc[j] += m0[j] * r;
    }
#pragma unroll
    for (int j = 0; j < 26; j++) red[w][j][lane] = acc[j];
    __syncthreads();
    for (int o = threadIdx.x; o < 26 * 64; o += 256) {
        int j = o >> 6, sdl = o & 63;
        float s = red[0][j][sdl] + red[1][j][sdl] + red[2][j][sdl] + red[3][j][sdl];
        float v = h[sd0 + sdl] - s;
        float* dst;
        if (j == 0) dst = rec0;
        else if (j <= 12) dst = x24 + (size_t)(j - 1) * SD;
        else if (j == 13) dst = x3;
        else dst = x24 + (size_t)(12 + j - 14) * SD;
        dst[sd0 + sdl] = v;
    }
}

// ---------------- wave LayerNorm helper (768 elems, 64 lanes, 12/lane)
__device__ inline void wave_ln(float (&vals)[12], int lane, const float* __restrict__ g,
                               const float* __restrict__ b) {
    float s = 0.f;
#pragma unroll
    for (int i = 0; i < 12; i++) s += vals[i];
#pragma unroll
    for (int m = 32; m >= 1; m >>= 1) s += __shfl_xor(s, m, 64);
    float mean = s * (1.f / DD);
    float vs = 0.f;
#pragma unroll
    for (int i = 0; i < 12; i++) { float d = vals[i] - mean; vs += d * d; }
#pragma unroll
    for (int m = 32; m >= 1; m >>= 1) vs += __shfl_xor(vs, m, 64);
    float rstd = rsqrtf(vs * (1.f / DD) + 1e-5f);
#pragma unroll
    for (int i = 0; i < 12; i++)
        vals[i] = (vals[i] - mean) * rstd * g[lane + 64 * i] + b[lane + 64 * i];
}

// ---------------- LayerNorm: wave per row; optional f32 and bf16 outputs
__global__ __launch_bounds__(64) void k_ln(const float* __restrict__ in, float* __restrict__ outf,
                                           u16* __restrict__ outb,
                                           const float* __restrict__ g, const float* __restrict__ b,
                                           int R) {
    int row = blockIdx.x;
    if (row >= R) return;
    int lane = threadIdx.x;
    const float* x = in + (size_t)row * DD;
    float vals[12];
#pragma unroll
    for (int i = 0; i < 12; i++) vals[i] = x[lane + 64 * i];
    wave_ln(vals, lane, g, b);
#pragma unroll
    for (int i = 0; i < 12; i++) {
        int d = lane + 64 * i;
        if (outf) outf[(size_t)row * DD + d] = vals[i];
        if (outb) outb[(size_t)row * DD + d] = f2bf(vals[i]);
    }
}

// ---------------- fused MLP-A LN: z0=ln2(resid), z1=ln2(ln1(x3)), z2..13=ln2(tmp24[12+z-2])
__global__ __launch_bounds__(64) void k_lnA(const float* __restrict__ resid,
                                            const float* __restrict__ x3,
                                            const float* __restrict__ tmp24,
                                            u16* __restrict__ mlpAb,
                                            const float* __restrict__ l1g, const float* __restrict__ l1b,
                                            const float* __restrict__ l2g, const float* __restrict__ l2b) {
    int row = blockIdx.x;            // 14*SS rows
    int z = row >> 7, s = row & 127;
    int lane = threadIdx.x;
    const float* src;
    if (z == 0) src = resid + (size_t)s * DD;
    else if (z == 1) src = x3 + (size_t)s * DD;
    else src = tmp24 + (size_t)(10 + z) * SD + (size_t)s * DD;
    float vals[12];
#pragma unroll
    for (int i = 0; i < 12; i++) vals[i] = src[lane + 64 * i];
    if (z == 1) wave_ln(vals, lane, l1g, l1b);
    wave_ln(vals, lane, l2g, l2b);
    u16* o = mlpAb + (size_t)z * SD + (size_t)s * DD;
#pragma unroll
    for (int i = 0; i < 12; i++) o[lane + 64 * i] = f2bf(vals[i]);
}

// ---------------- bf16 MFMA GEMM: C[z] = A[z] @ BT[z%zMod]^T (+bias), M=128
__global__ __launch_bounds__(256) void k_mm(
    const u16* __restrict__ A, const u16* __restrict__ BT,
    const float* __restrict__ bias, void* __restrict__ Cv,
    int N, int K, int lda, int ldbt, int ldc,
    long long sA, long long sBT, long long sC, long long sBias,
    int zMod, int biasZmax, int mode) {
    __shared__ u16 As[128][40];
    __shared__ u16 Bs[64][40];
    int z = blockIdx.z;
    int zb = z % zMod;
    const u16* Ab = A + (size_t)z * sA;
    const u16* Bb = BT + (size_t)zb * sBT;
    int n0 = blockIdx.x * 64;
    int tid = threadIdx.x;
    int lane = tid & 63, wid = tid >> 6;
    int wm = (wid >> 1) * 64, wn = (wid & 1) * 32;
    int l15 = lane & 15, l4 = lane >> 4;
    int sr = tid >> 2, sseg = tid & 3;
    f32x4 acc[4][2];
#pragma unroll
    for (int i = 0; i < 4; i++) { acc[i][0] = (f32x4)0.f; acc[i][1] = (f32x4)0.f; }
    for (int k0 = 0; k0 < K; k0 += 32) {
        uint4 a0 = *(const uint4*)(Ab + (size_t)sr * lda + k0 + sseg * 8);
        uint4 a1 = *(const uint4*)(Ab + (size_t)(sr + 64) * lda + k0 + sseg * 8);
        uint4 bv = {0u, 0u, 0u, 0u};
        int n = n0 + sr;
        if (n < N) bv = *(const uint4*)(Bb + (size_t)n * ldbt + k0 + sseg * 8);
        *(uint4*)&As[sr][sseg * 8] = a0;
        *(uint4*)&As[sr + 64][sseg * 8] = a1;
        *(uint4*)&Bs[sr][sseg * 8] = bv;
        __syncthreads();
        short8 af[4], bfr[2];
#pragma unroll
        for (int i = 0; i < 4; i++) af[i] = *(const short8*)&As[wm + i * 16 + l15][l4 * 8];
#pragma unroll
        for (int j = 0; j < 2; j++) bfr[j] = *(const short8*)&Bs[wn + j * 16 + l15][l4 * 8];
#pragma unroll
        for (int i = 0; i < 4; i++)
#pragma unroll
            for (int j = 0; j < 2; j++)
                acc[i][j] = __builtin_amdgcn_mfma_f32_16x16x32_bf16(af[i], bfr[j], acc[i][j], 0, 0, 0);
        __syncthreads();
    }
    const float* bp = (bias != nullptr && z < biasZmax) ? bias + (size_t)zb * sBias : nullptr;
    if (mode == 0) {
        float* Cb = (float*)Cv + (size_t)z * sC;
#pragma unroll
        for (int i = 0; i < 4; i++) {
            int row = wm + i * 16 + l4 * 4;
#pragma unroll
            for (int j = 0; j < 2; j++) {
                int col = n0 + wn + j * 16 + l15;
                if (col >= N) continue;
                float bb = bp ? bp[col] : 0.f;
#pragma unroll
                for (int r = 0; r < 4; r++)
                    Cb[(size_t)(row + r) * ldc + col] = acc[i][j][r] + bb;
            }
        }
    } else {
        u16* Cb = (u16*)Cv + (size_t)z * sC;
#pragma unroll
        for (int i = 0; i < 4; i++) {
            int row = wm + i * 16 + l4 * 4;
#pragma unroll
            for (int j = 0; j < 2; j++) {
                int col = n0 + wn + j * 16 + l15;
                if (col >= N) continue;
                float bb = bp ? bp[col] : 0.f;
#pragma unroll
                for (int r = 0; r < 4; r++) {
                    float v = acc[i][j][r] + bb;
                    float c = v + 0.044715f * v * v * v;
                    float gv = 0.5f * v * (1.f + tanhf(0.7978845608028654f * c));
                    Cb[(size_t)(row + r) * ldc + col] = f2bf(gv);
                }
            }
        }
    }
}

// ---------------- fused causal attention on fused qkv [z][128][192] f32 -> ctx bf16
__global__ __launch_bounds__(256) void k_attn(const float* __restrict__ qkv,
                                              u16* __restrict__ ctx) {
    __shared__ float kv[SS * DHD];
    __shared__ float qs[16][DHD];
    __shared__ float sc[16][130];
    int z = blockIdx.y, s0 = blockIdx.x * 16;
    const float* base = qkv + (size_t)z * SS * 192;
    int tid = threadIdx.x;
    for (int idx = tid; idx < SS * DHD; idx += 256) {
        int t = idx >> 6, d = idx & 63;
        kv[idx] = base[t * 192 + 64 + d];
    }
    for (int idx = tid; idx < 16 * DHD; idx += 256) {
        int r = idx >> 6, d = idx & 63;
        qs[r][d] = base[(s0 + r) * 192 + d];
    }
    __syncthreads();
    int r = tid >> 4, tt = tid & 15;
    int s = s0 + r;
    float pl[8];
#pragma unroll
    for (int u = 0; u < 8; u++) {
        int t = tt + 16 * u;
        float dot;
        if (t <= s) {
            dot = 0.f;
            for (int d = 0; d < DHD; d++) dot += qs[r][d] * kv[t * DHD + d];
            dot *= 0.125f;
        } else {
            dot = -1e30f;
        }
        pl[u] = dot;
    }
    float mx = pl[0];
#pragma unroll
    for (int u = 1; u < 8; u++) mx = fmaxf(mx, pl[u]);
#pragma unroll
    for (int m = 1; m < 16; m <<= 1) mx = fmaxf(mx, __shfl_xor(mx, m, 16));
    float sum = 0.f;
#pragma unroll
    for (int u = 0; u < 8; u++) { pl[u] = __expf(pl[u] - mx); sum += pl[u]; }
#pragma unroll
    for (int m = 1; m < 16; m <<= 1) sum += __shfl_xor(sum, m, 16);
    float inv = 1.f / sum;
#pragma unroll
    for (int u = 0; u < 8; u++) sc[r][tt + 16 * u] = pl[u] * inv;
    __syncthreads();
    for (int idx = tid; idx < SS * DHD; idx += 256) {
        int t = idx >> 6, d = idx & 63;
        kv[idx] = base[t * 192 + 128 + d];
    }
    __syncthreads();
    int d = tid & 63, r0 = tid >> 6;
#pragma unroll
    for (int u = 0; u < 4; u++) {
        int rr = r0 + 4 * u;
        float a = 0.f;
        for (int t = 0; t < SS; t++) a += sc[rr][t] * kv[t * DHD + d];
        ctx[(size_t)z * SS * DHD + (size_t)(s0 + rr) * DHD + d] = f2bf(a);
    }
}

// ---------------- residual
__global__ void k_resid(const float* __restrict__ tmp, const float* __restrict__ proj_b_i,
                        const float* __restrict__ mproj_b_i, float* __restrict__ reci,
                        float* __restrict__ resid) {
    int sd = blockIdx.x * 256 + threadIdx.x;
    if (sd >= SD) return;
    int d = sd % DD;
    float a = reci[sd];
#pragma unroll
    for (int j = 0; j < 12; j++) {
        float v = tmp[(size_t)j * SD + sd];
        reci[(size_t)(1 + j) * SD + sd] = v;
        a += v;
    }
    resid[sd] = a + proj_b_i[d];
    reci[(size_t)27 * SD + sd] = mproj_b_i[d];
    reci[(size_t)28 * SD + sd] = proj_b_i[d];
}

// ---------------- c5 + new h
__global__ void k_c5h(const float* __restrict__ reci, const float* __restrict__ strm,
                      const float* __restrict__ resid, const float* __restrict__ mproj_b_i,
                      float* __restrict__ slot26, float* __restrict__ h) {
    int sd = blockIdx.x * 256 + threadIdx.x;
    if (sd >= SD) return;
    int d = sd % DD;
    float s4 = 0.f;
#pragma unroll
    for (int j = 14; j <= 25; j++) s4 += reci[(size_t)j * SD + sd];
    float st = strm[sd];
    slot26[sd] = st - reci[(size_t)13 * SD + sd] - s4;
    h[sd] = resid[sd] + st + mproj_b_i[d];
}

extern "C" void kernel_launch(void* const* d_in, const int* in_sizes, int n_in,
                              void* d_out, int out_size, void* d_ws, size_t ws_size,
                              hipStream_t stream) {
    const int* ids = (const int*)d_in[0];
    const int* rm = (const int*)d_in[2];
    const float* wte = (const float*)d_in[3];
    const float* wpe = (const float*)d_in[4];
    const float* qkv_w = (const float*)d_in[5];
    const float* qkv_b = (const float*)d_in[6];
    const float* proj_w = (const float*)d_in[7];
    const float* proj_b = (const float*)d_in[8];
    const float* ln1_g = (const float*)d_in[9];
    const float* ln1_b = (const float*)d_in[10];
    const float* ln2_g = (const float*)d_in[11];
    const float* ln2_b = (const float*)d_in[12];
    const float* fc_w = (const float*)d_in[13];
    const float* fc_b = (const float*)d_in[14];
    const float* mproj_w = (const float*)d_in[15];
    const float* mproj_b = (const float*)d_in[16];
    const float* lnf_g = (const float*)d_in[17];
    const float* lnf_b = (const float*)d_in[18];
    float* out = (float*)d_out;

    float* ws = (float*)d_ws;
    size_t off = 0;
    float* records = ws + off; off += (size_t)LL * NCC * SD;
    float* x24  = ws + off; off += (size_t)24 * SD;
    float* tmp24= ws + off; off += (size_t)24 * SD;
    float* h    = ws + off; off += SD;
    float* x3   = ws + off; off += SD;
    float* resid= ws + off; off += SD;
    float* strm = ws + off; off += SD;
    float* qkvf = ws + off; off += (size_t)24 * SS * 192;
    float* qkvbp= ws + off; off += (size_t)LL * 3 * DD;
    float* lmf  = ws + off; off += (size_t)LL * TMAX * 32;
    u16* xlnb  = (u16*)(ws + off); off += (size_t)24 * SD / 2;
    u16* mlpAb = (u16*)(ws + off); off += (size_t)14 * SD / 2;
    u16* hfcb  = (u16*)(ws + off); off += (size_t)14 * SF / 2;
    u16* ctxb  = (u16*)(ws + off); off += (size_t)24 * SS * DHD / 2;
    u16* lnfb  = (u16*)(ws + off); off += SD / 2;
    u16* qkvhT = (u16*)(ws + off); off += (size_t)HH * 192 * DD / 2;
    u16* fcT   = (u16*)(ws + off); off += (size_t)FF * DD / 2;
    u16* mprojT= (u16*)(ws + off); off += (size_t)DD * FF / 2;
    u16* projT = (u16*)(ws + off); off += (size_t)DD * DD / 2;
    u16* wteb  = (u16*)(ws + off); off += (size_t)VV * DD / 2;

    k_maskf<<<(LL * TMAX + 63) / 64, 64, 0, stream>>>(rm, lmf);
    k_embed<<<SD / 256, 256, 0, stream>>>(ids, wte, wpe, h);
    k_cvt<<<((VV * DD / 4) + 255) / 256, 256, 0, stream>>>(wte, wteb, VV * DD / 4);
    k_qkvb<<<(LL * 3 * DD + 255) / 256, 256, 0, stream>>>(qkv_b, qkvbp);

    for (int i = 0; i < LL; i++) {
        float* reci = records + (size_t)i * NCC * SD;
        const float* l1g = ln1_g + i * DD; const float* l1b = ln1_b + i * DD;
        const float* l2g = ln2_g + i * DD; const float* l2b = ln2_b + i * DD;

        k_wt<<<dim3(36, 12), 256, 0, stream>>>(qkv_w + (size_t)i * DD * 3 * DD, qkvhT, DD, 3 * DD, 1);
        k_wt<<<dim3(48, 12), 256, 0, stream>>>(fc_w + (size_t)i * DD * FF, fcT, DD, FF, 0);
        k_wt<<<dim3(12, 48), 256, 0, stream>>>(mproj_w + (size_t)i * FF * DD, mprojT, FF, DD, 0);
        k_wt<<<dim3(12, 12), 256, 0, stream>>>(proj_w + (size_t)i * DD * DD, projT, DD, DD, 0);

        k_check<<<SD / 64, 256, 0, stream>>>(records, lmf, h, reci, x24, x3, i);

        k_ln<<<24 * SS, 64, 0, stream>>>(x24, nullptr, xlnb, l1g, l1b, 24 * SS);
        k_mm<<<dim3(3, 1, 24), 256, 0, stream>>>(
            xlnb, qkvhT, qkvbp + (size_t)i * 3 * DD, qkvf,
            192, DD, DD, DD, 192, SD, (long long)192 * DD, (long long)SS * 192, 192, 12, 24, 0);
        k_attn<<<dim3(SS / 16, 24), 256, 0, stream>>>(qkvf, ctxb);
        k_mm<<<dim3(12, 1, 24), 256, 0, stream>>>(
            ctxb, projT, nullptr, tmp24,
            DD, DHD, DHD, DD, DD, (long long)SS * DHD, 64, SD, 0, 12, 0, 0);
        k_resid<<<SD / 256, 256, 0, stream>>>(tmp24, proj_b + i * DD, mproj_b + i * DD, reci, resid);

        k_lnA<<<14 * SS, 64, 0, stream>>>(resid, x3, tmp24, mlpAb, l1g, l1b, l2g, l2b);

        k_mm<<<dim3(48, 1, 14), 256, 0, stream>>>(
            mlpAb, fcT, fc_b + (size_t)i * FF, hfcb,
            FF, DD, DD, DD, FF, SD, 0, SF, 0, 1, 1, 1);
        k_mm<<<dim3(12, 1, 13), 256, 0, stream>>>(
            hfcb + SF, mprojT, nullptr, reci + (size_t)13 * SD,
            DD, FF, FF, FF, DD, SF, 0, SD, 0, 1, 0, 0);
        k_mm<<<dim3(12, 1, 1), 256, 0, stream>>>(
            hfcb, mprojT, nullptr, strm,
            DD, FF, FF, FF, DD, 0, 0, 0, 0, 1, 0, 0);

        k_c5h<<<SD / 256, 256, 0, stream>>>(reci, strm, resid, mproj_b + i * DD,
                                            reci + (size_t)26 * SD, h);
    }

    k_ln<<<SS, 64, 0, stream>>>(h, nullptr, lnfb, lnf_g, lnf_b, SS);
    k_mm<<<dim3((VV + 63) / 64, 1, 1), 256, 0, stream>>>(
        lnfb, wteb, nullptr, out,
        VV, DD, DD, DD, VV, 0, 0, 0, 0, 1, 0, 0);
}

// Round 4
// 3306.018 us; speedup vs baseline: 1.2044x; 1.2044x over previous
//
#include <hip/hip_runtime.h>

#define SS 128
#define DD 768
#define HH 12
#define DHD 64
#define FF 3072
#define VV 50257
#define NCC 29
#define LL 12
#define SD (SS*DD)      // 98304
#define SF (SS*FF)      // 393216
#define TMAX (LL*NCC)   // 348

typedef unsigned short u16;
typedef __attribute__((ext_vector_type(8))) short short8;
typedef __attribute__((ext_vector_type(4))) float f32x4;

__device__ inline u16 f2bf(float f) {
    union { float f; unsigned u; } x; x.f = f;
    unsigned r = x.u + 0x7fffu + ((x.u >> 16) & 1u);
    return (u16)(r >> 16);
}

// ---------------- bitmask pack: lmu[i][t] bit j = rm[i*29+j][t]
__global__ void k_masku(const int* __restrict__ rm, unsigned* __restrict__ lmu) {
    int idx = blockIdx.x * 256 + threadIdx.x;
    if (idx >= LL * TMAX) return;
    int i = idx / TMAX, t = idx % TMAX;
    unsigned m = 0;
    for (int j = 0; j < 26; j++)
        m |= (unsigned)(rm[(size_t)(i * NCC + j) * TMAX + t] & 1) << j;
    lmu[idx] = m;
}

// ---------------- embedding
__global__ void k_embed(const int* __restrict__ ids, const float* __restrict__ wte,
                        const float* __restrict__ wpe, float* __restrict__ h) {
    int sd = blockIdx.x * 256 + threadIdx.x;
    if (sd >= SD) return;
    int s = sd / DD, d = sd % DD;
    h[sd] = wte[(size_t)ids[s] * DD + d] + wpe[sd];
}

// ---------------- f32 -> bf16 elementwise (wte)
__global__ void k_cvt(const float* __restrict__ in, u16* __restrict__ out, int n4) {
    int i = blockIdx.x * 256 + threadIdx.x;
    if (i >= n4) return;
    float4 v = *(const float4*)(in + (size_t)i * 4);
    u16* o = out + (size_t)i * 4;
    o[0] = f2bf(v.x); o[1] = f2bf(v.y); o[2] = f2bf(v.z); o[3] = f2bf(v.w);
}

// ---------------- qkv bias pack: [L][3*D] -> [L][12 heads][192]
__global__ void k_qkvb(const float* __restrict__ qkv_b, float* __restrict__ qkvbp) {
    int idx = blockIdx.x * 256 + threadIdx.x;
    if (idx >= LL * 3 * DD) return;
    int l = idx / (3 * DD), r = idx % (3 * DD);
    int p = r / DD, rem = r % DD, h = rem / DHD, j = rem % DHD;
    qkvbp[(size_t)l * 3 * DD + h * 192 + p * DHD + j] = qkv_b[idx];
}

// ---------------- weight transpose-convert (batched over layers via z):
// W[z][K][N] f32 -> WT[z][N][K] bf16
__global__ __launch_bounds__(256) void k_wt(const float* __restrict__ W, u16* __restrict__ WT,
                                            int K, int N, int remap,
                                            long long sW, long long sWT) {
    __shared__ float T[64][65];
    const float* Wb = W + (size_t)blockIdx.z * sW;
    u16* WTb = WT + (size_t)blockIdx.z * sWT;
    int n0 = blockIdx.x * 64, k0 = blockIdx.y * 64;
    int c = threadIdx.x & 63, r0 = threadIdx.x >> 6;
#pragma unroll
    for (int i = 0; i < 16; i++) {
        int r = r0 + 4 * i;
        T[r][c] = Wb[(size_t)(k0 + r) * N + n0 + c];
    }
    __syncthreads();
    int ob = n0 >> 6;
    if (remap) { int p = ob / 12, h = ob % 12; ob = h * 3 + p; }
    size_t orow0 = (size_t)ob * 64;
#pragma unroll
    for (int i = 0; i < 16; i++) {
        int a = r0 + 4 * i;
        WTb[(orow0 + a) * K + k0 + c] = f2bf(T[c][a]);
    }
}

// ---------------- checks: one wave per 64-sd stripe, 8-deep prefetch,
// masks scalarized via readfirstlane -> s_cselect + v_fmac(sgpr)
__global__ __launch_bounds__(64) void k_check(
    const float* __restrict__ records, const unsigned* __restrict__ lmu,
    const float* __restrict__ h, float* __restrict__ rec0, float* __restrict__ x24,
    float* __restrict__ x3, int layer) {
    int sd = blockIdx.x * 64 + threadIdx.x;
    float acc[26];
#pragma unroll
    for (int j = 0; j < 26; j++) acc[j] = 0.f;
    const unsigned* lm = lmu + layer * TMAX;
    int T = layer * NCC;
    const float* rp = records + sd;
    int t = 0;
    for (; t + 8 <= T; t += 8) {
        float r[8];
        unsigned mv[8];
#pragma unroll
        for (int u = 0; u < 8; u++) r[u] = rp[(size_t)(t + u) * SD];
#pragma unroll
        for (int u = 0; u < 8; u++) mv[u] = lm[t + u];
#pragma unroll
        for (int u = 0; u < 8; u++) {
            unsigned m = __builtin_amdgcn_readfirstlane(mv[u]);
#pragma unroll
            for (int j = 0; j < 26; j++)
                acc[j] = fmaf((m & (1u << j)) ? 1.0f : 0.0f, r[u], acc[j]);
        }
    }
    for (; t < T; t++) {
        float r = rp[(size_t)t * SD];
        unsigned m = __builtin_amdgcn_readfirstlane(lm[t]);
#pragma unroll
        for (int j = 0; j < 26; j++)
            acc[j] = fmaf((m & (1u << j)) ? 1.0f : 0.0f, r, acc[j]);
    }
    float hv = h[sd];
    rec0[sd] = hv - acc[0];
#pragma unroll
    for (int j = 0; j < 12; j++) x24[(size_t)j * SD + sd] = hv - acc[1 + j];
    x3[sd] = hv - acc[13];
#pragma unroll
    for (int j = 0; j < 12; j++) x24[(size_t)(12 + j) * SD + sd] = hv - acc[14 + j];
}

// ---------------- wave LayerNorm helper
__device__ inline void wave_ln(float (&vals)[12], int lane, const float* __restrict__ g,
                               const float* __restrict__ b) {
    float s = 0.f;
#pragma unroll
    for (int i = 0; i < 12; i++) s += vals[i];
#pragma unroll
    for (int m = 32; m >= 1; m >>= 1) s += __shfl_xor(s, m, 64);
    float mean = s * (1.f / DD);
    float vs = 0.f;
#pragma unroll
    for (int i = 0; i < 12; i++) { float d = vals[i] - mean; vs += d * d; }
#pragma unroll
    for (int m = 32; m >= 1; m >>= 1) vs += __shfl_xor(vs, m, 64);
    float rstd = rsqrtf(vs * (1.f / DD) + 1e-5f);
#pragma unroll
    for (int i = 0; i < 12; i++)
        vals[i] = (vals[i] - mean) * rstd * g[lane + 64 * i] + b[lane + 64 * i];
}

// ---------------- LayerNorm: wave per row
__global__ __launch_bounds__(64) void k_ln(const float* __restrict__ in, float* __restrict__ outf,
                                           u16* __restrict__ outb,
                                           const float* __restrict__ g, const float* __restrict__ b,
                                           int R) {
    int row = blockIdx.x;
    if (row >= R) return;
    int lane = threadIdx.x;
    const float* x = in + (size_t)row * DD;
    float vals[12];
#pragma unroll
    for (int i = 0; i < 12; i++) vals[i] = x[lane + 64 * i];
    wave_ln(vals, lane, g, b);
#pragma unroll
    for (int i = 0; i < 12; i++) {
        int d = lane + 64 * i;
        if (outf) outf[(size_t)row * DD + d] = vals[i];
        if (outb) outb[(size_t)row * DD + d] = f2bf(vals[i]);
    }
}

// ---------------- fused MLP-A LN
__global__ __launch_bounds__(64) void k_lnA(const float* __restrict__ resid,
                                            const float* __restrict__ x3,
                                            const float* __restrict__ tmp24,
                                            u16* __restrict__ mlpAb,
                                            const float* __restrict__ l1g, const float* __restrict__ l1b,
                                            const float* __restrict__ l2g, const float* __restrict__ l2b) {
    int row = blockIdx.x;            // 14*SS rows
    int z = row >> 7, s = row & 127;
    int lane = threadIdx.x;
    const float* src;
    if (z == 0) src = resid + (size_t)s * DD;
    else if (z == 1) src = x3 + (size_t)s * DD;
    else src = tmp24 + (size_t)(10 + z) * SD + (size_t)s * DD;
    float vals[12];
#pragma unroll
    for (int i = 0; i < 12; i++) vals[i] = src[lane + 64 * i];
    if (z == 1) wave_ln(vals, lane, l1g, l1b);
    wave_ln(vals, lane, l2g, l2b);
    u16* o = mlpAb + (size_t)z * SD + (size_t)s * DD;
#pragma unroll
    for (int i = 0; i < 12; i++) o[lane + 64 * i] = f2bf(vals[i]);
}

// ---------------- bf16 MFMA GEMM: C[z] = A[z] @ BT[z%zMod]^T (+bias), M=128
__global__ __launch_bounds__(256) void k_mm(
    const u16* __restrict__ A, const u16* __restrict__ BT,
    const float* __restrict__ bias, void* __restrict__ Cv,
    int N, int K, int lda, int ldbt, int ldc,
    long long sA, long long sBT, long long sC, long long sBias,
    int zMod, int biasZmax, int mode) {
    __shared__ u16 As[128][40];
    __shared__ u16 Bs[64][40];
    int z = blockIdx.z;
    int zb = z % zMod;
    const u16* Ab = A + (size_t)z * sA;
    const u16* Bb = BT + (size_t)zb * sBT;
    int n0 = blockIdx.x * 64;
    int tid = threadIdx.x;
    int lane = tid & 63, wid = tid >> 6;
    int wm = (wid >> 1) * 64, wn = (wid & 1) * 32;
    int l15 = lane & 15, l4 = lane >> 4;
    int sr = tid >> 2, sseg = tid & 3;
    f32x4 acc[4][2];
#pragma unroll
    for (int i = 0; i < 4; i++) { acc[i][0] = (f32x4)0.f; acc[i][1] = (f32x4)0.f; }
    for (int k0 = 0; k0 < K; k0 += 32) {
        uint4 a0 = *(const uint4*)(Ab + (size_t)sr * lda + k0 + sseg * 8);
        uint4 a1 = *(const uint4*)(Ab + (size_t)(sr + 64) * lda + k0 + sseg * 8);
        uint4 bv = {0u, 0u, 0u, 0u};
        int n = n0 + sr;
        if (n < N) bv = *(const uint4*)(Bb + (size_t)n * ldbt + k0 + sseg * 8);
        *(uint4*)&As[sr][sseg * 8] = a0;
        *(uint4*)&As[sr + 64][sseg * 8] = a1;
        *(uint4*)&Bs[sr][sseg * 8] = bv;
        __syncthreads();
        short8 af[4], bfr[2];
#pragma unroll
        for (int i = 0; i < 4; i++) af[i] = *(const short8*)&As[wm + i * 16 + l15][l4 * 8];
#pragma unroll
        for (int j = 0; j < 2; j++) bfr[j] = *(const short8*)&Bs[wn + j * 16 + l15][l4 * 8];
#pragma unroll
        for (int i = 0; i < 4; i++)
#pragma unroll
            for (int j = 0; j < 2; j++)
                acc[i][j] = __builtin_amdgcn_mfma_f32_16x16x32_bf16(af[i], bfr[j], acc[i][j], 0, 0, 0);
        __syncthreads();
    }
    const float* bp = (bias != nullptr && z < biasZmax) ? bias + (size_t)zb * sBias : nullptr;
    if (mode == 0) {
        float* Cb = (float*)Cv + (size_t)z * sC;
#pragma unroll
        for (int i = 0; i < 4; i++) {
            int row = wm + i * 16 + l4 * 4;
#pragma unroll
            for (int j = 0; j < 2; j++) {
                int col = n0 + wn + j * 16 + l15;
                if (col >= N) continue;
                float bb = bp ? bp[col] : 0.f;
#pragma unroll
                for (int r = 0; r < 4; r++)
                    Cb[(size_t)(row + r) * ldc + col] = acc[i][j][r] + bb;
            }
        }
    } else {
        u16* Cb = (u16*)Cv + (size_t)z * sC;
#pragma unroll
        for (int i = 0; i < 4; i++) {
            int row = wm + i * 16 + l4 * 4;
#pragma unroll
            for (int j = 0; j < 2; j++) {
                int col = n0 + wn + j * 16 + l15;
                if (col >= N) continue;
                float bb = bp ? bp[col] : 0.f;
#pragma unroll
                for (int r = 0; r < 4; r++) {
                    float v = acc[i][j][r] + bb;
                    float c = v + 0.044715f * v * v * v;
                    float gv = 0.5f * v * (1.f + tanhf(0.7978845608028654f * c));
                    Cb[(size_t)(row + r) * ldc + col] = f2bf(gv);
                }
            }
        }
    }
}

// ---------------- fused causal attention on fused qkv [z][128][192] f32 -> ctx bf16
__global__ __launch_bounds__(256) void k_attn(const float* __restrict__ qkv,
                                              u16* __restrict__ ctx) {
    __shared__ float kv[SS * DHD];
    __shared__ float qs[16][DHD];
    __shared__ float sc[16][130];
    int z = blockIdx.y, s0 = blockIdx.x * 16;
    const float* base = qkv + (size_t)z * SS * 192;
    int tid = threadIdx.x;
    for (int idx = tid; idx < SS * DHD; idx += 256) {
        int t = idx >> 6, d = idx & 63;
        kv[idx] = base[t * 192 + 64 + d];
    }
    for (int idx = tid; idx < 16 * DHD; idx += 256) {
        int r = idx >> 6, d = idx & 63;
        qs[r][d] = base[(s0 + r) * 192 + d];
    }
    __syncthreads();
    int r = tid >> 4, tt = tid & 15;
    int s = s0 + r;
    float pl[8];
#pragma unroll
    for (int u = 0; u < 8; u++) {
        int t = tt + 16 * u;
        float dot;
        if (t <= s) {
            dot = 0.f;
            for (int d = 0; d < DHD; d++) dot += qs[r][d] * kv[t * DHD + d];
            dot *= 0.125f;
        } else {
            dot = -1e30f;
        }
        pl[u] = dot;
    }
    float mx = pl[0];
#pragma unroll
    for (int u = 1; u < 8; u++) mx = fmaxf(mx, pl[u]);
#pragma unroll
    for (int m = 1; m < 16; m <<= 1) mx = fmaxf(mx, __shfl_xor(mx, m, 16));
    float sum = 0.f;
#pragma unroll
    for (int u = 0; u < 8; u++) { pl[u] = __expf(pl[u] - mx); sum += pl[u]; }
#pragma unroll
    for (int m = 1; m < 16; m <<= 1) sum += __shfl_xor(sum, m, 16);
    float inv = 1.f / sum;
#pragma unroll
    for (int u = 0; u < 8; u++) sc[r][tt + 16 * u] = pl[u] * inv;
    __syncthreads();
    for (int idx = tid; idx < SS * DHD; idx += 256) {
        int t = idx >> 6, d = idx & 63;
        kv[idx] = base[t * 192 + 128 + d];
    }
    __syncthreads();
    int d = tid & 63, r0 = tid >> 6;
#pragma unroll
    for (int u = 0; u < 4; u++) {
        int rr = r0 + 4 * u;
        float a = 0.f;
        for (int t = 0; t < SS; t++) a += sc[rr][t] * kv[t * DHD + d];
        ctx[(size_t)z * SS * DHD + (size_t)(s0 + rr) * DHD + d] = f2bf(a);
    }
}

// ---------------- residual
__global__ void k_resid(const float* __restrict__ tmp, const float* __restrict__ proj_b_i,
                        const float* __restrict__ mproj_b_i, float* __restrict__ reci,
                        float* __restrict__ resid) {
    int sd = blockIdx.x * 256 + threadIdx.x;
    if (sd >= SD) return;
    int d = sd % DD;
    float a = reci[sd];
#pragma unroll
    for (int j = 0; j < 12; j++) {
        float v = tmp[(size_t)j * SD + sd];
        reci[(size_t)(1 + j) * SD + sd] = v;
        a += v;
    }
    resid[sd] = a + proj_b_i[d];
    reci[(size_t)27 * SD + sd] = mproj_b_i[d];
    reci[(size_t)28 * SD + sd] = proj_b_i[d];
}

// ---------------- c5 + new h
__global__ void k_c5h(const float* __restrict__ reci, const float* __restrict__ strm,
                      const float* __restrict__ resid, const float* __restrict__ mproj_b_i,
                      float* __restrict__ slot26, float* __restrict__ h) {
    int sd = blockIdx.x * 256 + threadIdx.x;
    if (sd >= SD) return;
    int d = sd % DD;
    float s4 = 0.f;
#pragma unroll
    for (int j = 14; j <= 25; j++) s4 += reci[(size_t)j * SD + sd];
    float st = strm[sd];
    slot26[sd] = st - reci[(size_t)13 * SD + sd] - s4;
    h[sd] = resid[sd] + st + mproj_b_i[d];
}

extern "C" void kernel_launch(void* const* d_in, const int* in_sizes, int n_in,
                              void* d_out, int out_size, void* d_ws, size_t ws_size,
                              hipStream_t stream) {
    const int* ids = (const int*)d_in[0];
    const int* rm = (const int*)d_in[2];
    const float* wte = (const float*)d_in[3];
    const float* wpe = (const float*)d_in[4];
    const float* qkv_w = (const float*)d_in[5];
    const float* qkv_b = (const float*)d_in[6];
    const float* proj_w = (const float*)d_in[7];
    const float* proj_b = (const float*)d_in[8];
    const float* ln1_g = (const float*)d_in[9];
    const float* ln1_b = (const float*)d_in[10];
    const float* ln2_g = (const float*)d_in[11];
    const float* ln2_b = (const float*)d_in[12];
    const float* fc_w = (const float*)d_in[13];
    const float* fc_b = (const float*)d_in[14];
    const float* mproj_w = (const float*)d_in[15];
    const float* mproj_b = (const float*)d_in[16];
    const float* lnf_g = (const float*)d_in[17];
    const float* lnf_b = (const float*)d_in[18];
    float* out = (float*)d_out;

    float* ws = (float*)d_ws;
    size_t off = 0;
    float* records = ws + off; off += (size_t)LL * NCC * SD;
    float* x24  = ws + off; off += (size_t)24 * SD;
    float* tmp24= ws + off; off += (size_t)24 * SD;
    float* h    = ws + off; off += SD;
    float* x3   = ws + off; off += SD;
    float* resid= ws + off; off += SD;
    float* strm = ws + off; off += SD;
    float* qkvf = ws + off; off += (size_t)24 * SS * 192;
    float* qkvbp= ws + off; off += (size_t)LL * 3 * DD;
    u16* xlnb  = (u16*)(ws + off); off += (size_t)24 * SD / 2;
    u16* mlpAb = (u16*)(ws + off); off += (size_t)14 * SD / 2;
    u16* hfcb  = (u16*)(ws + off); off += (size_t)14 * SF / 2;
    u16* ctxb  = (u16*)(ws + off); off += (size_t)24 * SS * DHD / 2;
    u16* lnfb  = (u16*)(ws + off); off += SD / 2;
    u16* qkvhT = (u16*)(ws + off); off += (size_t)LL * 2304 * DD / 2;
    u16* fcT   = (u16*)(ws + off); off += (size_t)LL * FF * DD / 2;
    u16* mprojT= (u16*)(ws + off); off += (size_t)LL * DD * FF / 2;
    u16* projT = (u16*)(ws + off); off += (size_t)LL * DD * DD / 2;
    u16* wteb  = (u16*)(ws + off); off += (size_t)VV * DD / 2;
    unsigned* lmu = (unsigned*)(ws + off);

    k_masku<<<(LL * TMAX + 255) / 256, 256, 0, stream>>>(rm, lmu);
    k_embed<<<SD / 256, 256, 0, stream>>>(ids, wte, wpe, h);
    k_cvt<<<((VV * DD / 4) + 255) / 256, 256, 0, stream>>>(wte, wteb, VV * DD / 4);
    k_qkvb<<<(LL * 3 * DD + 255) / 256, 256, 0, stream>>>(qkv_b, qkvbp);
    // all-layer weight transpose-converts (batched, out of the layer loop)
    k_wt<<<dim3(36, 12, 12), 256, 0, stream>>>(qkv_w, qkvhT, DD, 3 * DD, 1,
                                               (long long)DD * 3 * DD, (long long)2304 * DD);
    k_wt<<<dim3(48, 12, 12), 256, 0, stream>>>(fc_w, fcT, DD, FF, 0,
                                               (long long)DD * FF, (long long)FF * DD);
    k_wt<<<dim3(12, 48, 12), 256, 0, stream>>>(mproj_w, mprojT, FF, DD, 0,
                                               (long long)FF * DD, (long long)DD * FF);
    k_wt<<<dim3(12, 12, 12), 256, 0, stream>>>(proj_w, projT, DD, DD, 0,
                                               (long long)DD * DD, (long long)DD * DD);

    for (int i = 0; i < LL; i++) {
        float* reci = records + (size_t)i * NCC * SD;
        const float* l1g = ln1_g + i * DD; const float* l1b = ln1_b + i * DD;
        const float* l2g = ln2_g + i * DD; const float* l2b = ln2_b + i * DD;
        const u16* qkvhTi = qkvhT + (size_t)i * 2304 * DD;
        const u16* fcTi = fcT + (size_t)i * FF * DD;
        const u16* mprojTi = mprojT + (size_t)i * DD * FF;
        const u16* projTi = projT + (size_t)i * DD * DD;

        k_check<<<SD / 64, 64, 0, stream>>>(records, lmu, h, reci, x24, x3, i);

        k_ln<<<24 * SS, 64, 0, stream>>>(x24, nullptr, xlnb, l1g, l1b, 24 * SS);
        k_mm<<<dim3(3, 1, 24), 256, 0, stream>>>(
            xlnb, qkvhTi, qkvbp + (size_t)i * 3 * DD, qkvf,
            192, DD, DD, DD, 192, SD, (long long)192 * DD, (long long)SS * 192, 192, 12, 24, 0);
        k_attn<<<dim3(SS / 16, 24), 256, 0, stream>>>(qkvf, ctxb);
        k_mm<<<dim3(12, 1, 24), 256, 0, stream>>>(
            ctxb, projTi, nullptr, tmp24,
            DD, DHD, DHD, DD, DD, (long long)SS * DHD, 64, SD, 0, 12, 0, 0);
        k_resid<<<SD / 256, 256, 0, stream>>>(tmp24, proj_b + i * DD, mproj_b + i * DD, reci, resid);

        k_lnA<<<14 * SS, 64, 0, stream>>>(resid, x3, tmp24, mlpAb, l1g, l1b, l2g, l2b);

        k_mm<<<dim3(48, 1, 14), 256, 0, stream>>>(
            mlpAb, fcTi, fc_b + (size_t)i * FF, hfcb,
            FF, DD, DD, DD, FF, SD, 0, SF, 0, 1, 1, 1);
        k_mm<<<dim3(12, 1, 13), 256, 0, stream>>>(
            hfcb + SF, mprojTi, nullptr, reci + (size_t)13 * SD,
            DD, FF, FF, FF, DD, SF, 0, SD, 0, 1, 0, 0);
        k_mm<<<dim3(12, 1, 1), 256, 0, stream>>>(
            hfcb, mprojTi, nullptr, strm,
            DD, FF, FF, FF, DD, 0, 0, 0, 0, 1, 0, 0);

        k_c5h<<<SD / 256, 256, 0, stream>>>(reci, strm, resid, mproj_b + i * DD,
                                            reci + (size_t)26 * SD, h);
    }

    k_ln<<<SS, 64, 0, stream>>>(h, nullptr, lnfb, lnf_g, lnf_b, SS);
    k_mm<<<dim3((VV + 63) / 64, 1, 1), 256, 0, stream>>>(
        lnfb, wteb, nullptr, out,
        VV, DD, DD, DD, VV, 0, 0, 0, 0, 1, 0, 0);
}

// Round 5
// 2534.666 us; speedup vs baseline: 1.5709x; 1.3043x over previous
//
#include <hip/hip_runtime.h>

#define SS 128
#define DD 768
#define HH 12
#define DHD 64
#define FF 3072
#define VV 50257
#define NCC 29
#define LL 12
#define SD (SS*DD)      // 98304
#define SF (SS*FF)      // 393216
#define TMAX (LL*NCC)   // 348

typedef unsigned short u16;
typedef __attribute__((ext_vector_type(8))) short short8;
typedef __attribute__((ext_vector_type(4))) float f32x4;

__device__ inline u16 f2bf(float f) {
    union { float f; unsigned u; } x; x.f = f;
    unsigned r = x.u + 0x7fffu + ((x.u >> 16) & 1u);
    return (u16)(r >> 16);
}

// ---------------- bitmask pack: lmu[i][t] bit j = rm[i*29+j][t]
__global__ void k_masku(const int* __restrict__ rm, unsigned* __restrict__ lmu) {
    int idx = blockIdx.x * 256 + threadIdx.x;
    if (idx >= LL * TMAX) return;
    int i = idx / TMAX, t = idx % TMAX;
    unsigned m = 0;
    for (int j = 0; j < 26; j++)
        m |= (unsigned)(rm[(size_t)(i * NCC + j) * TMAX + t] & 1) << j;
    lmu[idx] = m;
}

// ---------------- embedding
__global__ void k_embed(const int* __restrict__ ids, const float* __restrict__ wte,
                        const float* __restrict__ wpe, float* __restrict__ h) {
    int sd = blockIdx.x * 256 + threadIdx.x;
    if (sd >= SD) return;
    int s = sd / DD, d = sd % DD;
    h[sd] = wte[(size_t)ids[s] * DD + d] + wpe[sd];
}

// ---------------- f32 -> bf16 elementwise (wte)
__global__ void k_cvt(const float* __restrict__ in, u16* __restrict__ out, int n4) {
    int i = blockIdx.x * 256 + threadIdx.x;
    if (i >= n4) return;
    float4 v = *(const float4*)(in + (size_t)i * 4);
    u16* o = out + (size_t)i * 4;
    o[0] = f2bf(v.x); o[1] = f2bf(v.y); o[2] = f2bf(v.z); o[3] = f2bf(v.w);
}

// ---------------- qkv bias pack: [L][3*D] -> [L][12 heads][192]
__global__ void k_qkvb(const float* __restrict__ qkv_b, float* __restrict__ qkvbp) {
    int idx = blockIdx.x * 256 + threadIdx.x;
    if (idx >= LL * 3 * DD) return;
    int l = idx / (3 * DD), r = idx % (3 * DD);
    int p = r / DD, rem = r % DD, h = rem / DHD, j = rem % DHD;
    qkvbp[(size_t)l * 3 * DD + h * 192 + p * DHD + j] = qkv_b[idx];
}

// ---------------- weight transpose-convert (batched over layers via z)
__global__ __launch_bounds__(256) void k_wt(const float* __restrict__ W, u16* __restrict__ WT,
                                            int K, int N, int remap,
                                            long long sW, long long sWT) {
    __shared__ float T[64][65];
    const float* Wb = W + (size_t)blockIdx.z * sW;
    u16* WTb = WT + (size_t)blockIdx.z * sWT;
    int n0 = blockIdx.x * 64, k0 = blockIdx.y * 64;
    int c = threadIdx.x & 63, r0 = threadIdx.x >> 6;
#pragma unroll
    for (int i = 0; i < 16; i++) {
        int r = r0 + 4 * i;
        T[r][c] = Wb[(size_t)(k0 + r) * N + n0 + c];
    }
    __syncthreads();
    int ob = n0 >> 6;
    if (remap) { int p = ob / 12, h = ob % 12; ob = h * 3 + p; }
    size_t orow0 = (size_t)ob * 64;
#pragma unroll
    for (int i = 0; i < 16; i++) {
        int a = r0 + 4 * i;
        WTb[(orow0 + a) * K + k0 + c] = f2bf(T[c][a]);
    }
}

// ---------------- checks: 4 waves t-split over one 64-sd stripe,
// bitmask scalarized via readfirstlane, 8-deep prefetch, LDS cross-wave reduce
__global__ __launch_bounds__(256) void k_check(
    const float* __restrict__ records, const unsigned* __restrict__ lmu,
    const float* __restrict__ h, float* __restrict__ rec0, float* __restrict__ x24,
    float* __restrict__ x3, int layer) {
    __shared__ float red[4][26][64];
    int lane = threadIdx.x & 63, w = threadIdx.x >> 6;
    int sd0 = blockIdx.x * 64;
    int sd = sd0 + lane;
    int T = layer * NCC;
    int Tq = (T + 3) >> 2;
    int tb = w * Tq, te = tb + Tq; if (te > T) te = T;
    float acc[26];
#pragma unroll
    for (int j = 0; j < 26; j++) acc[j] = 0.f;
    const unsigned* lm = lmu + layer * TMAX;
    const float* rp = records + sd;
    int t = tb;
    for (; t + 8 <= te; t += 8) {
        float r[8];
        unsigned mv[8];
#pragma unroll
        for (int u = 0; u < 8; u++) r[u] = rp[(size_t)(t + u) * SD];
#pragma unroll
        for (int u = 0; u < 8; u++) mv[u] = lm[t + u];
#pragma unroll
        for (int u = 0; u < 8; u++) {
            unsigned m = __builtin_amdgcn_readfirstlane(mv[u]);
#pragma unroll
            for (int j = 0; j < 26; j++)
                acc[j] = fmaf((m & (1u << j)) ? 1.0f : 0.0f, r[u], acc[j]);
        }
    }
    for (; t < te; t++) {
        float r = rp[(size_t)t * SD];
        unsigned m = __builtin_amdgcn_readfirstlane(lm[t]);
#pragma unroll
        for (int j = 0; j < 26; j++)
            acc[j] = fmaf((m & (1u << j)) ? 1.0f : 0.0f, r, acc[j]);
    }
#pragma unroll
    for (int j = 0; j < 26; j++) red[w][j][lane] = acc[j];
    __syncthreads();
    for (int o = threadIdx.x; o < 26 * 64; o += 256) {
        int j = o >> 6, sdl = o & 63;
        float s = red[0][j][sdl] + red[1][j][sdl] + red[2][j][sdl] + red[3][j][sdl];
        float v = h[sd0 + sdl] - s;
        float* dst;
        if (j == 0) dst = rec0;
        else if (j <= 12) dst = x24 + (size_t)(j - 1) * SD;
        else if (j == 13) dst = x3;
        else dst = x24 + (size_t)(12 + j - 14) * SD;
        dst[sd0 + sdl] = v;
    }
}

// ---------------- wave LayerNorm helper
__device__ inline void wave_ln(float (&vals)[12], int lane, const float* __restrict__ g,
                               const float* __restrict__ b) {
    float s = 0.f;
#pragma unroll
    for (int i = 0; i < 12; i++) s += vals[i];
#pragma unroll
    for (int m = 32; m >= 1; m >>= 1) s += __shfl_xor(s, m, 64);
    float mean = s * (1.f / DD);
    float vs = 0.f;
#pragma unroll
    for (int i = 0; i < 12; i++) { float d = vals[i] - mean; vs += d * d; }
#pragma unroll
    for (int m = 32; m >= 1; m >>= 1) vs += __shfl_xor(vs, m, 64);
    float rstd = rsqrtf(vs * (1.f / DD) + 1e-5f);
#pragma unroll
    for (int i = 0; i < 12; i++)
        vals[i] = (vals[i] - mean) * rstd * g[lane + 64 * i] + b[lane + 64 * i];
}

// ---------------- LayerNorm: wave per row
__global__ __launch_bounds__(64) void k_ln(const float* __restrict__ in, float* __restrict__ outf,
                                           u16* __restrict__ outb,
                                           const float* __restrict__ g, const float* __restrict__ b,
                                           int R) {
    int row = blockIdx.x;
    if (row >= R) return;
    int lane = threadIdx.x;
    const float* x = in + (size_t)row * DD;
    float vals[12];
#pragma unroll
    for (int i = 0; i < 12; i++) vals[i] = x[lane + 64 * i];
    wave_ln(vals, lane, g, b);
#pragma unroll
    for (int i = 0; i < 12; i++) {
        int d = lane + 64 * i;
        if (outf) outf[(size_t)row * DD + d] = vals[i];
        if (outb) outb[(size_t)row * DD + d] = f2bf(vals[i]);
    }
}

// ---------------- fused MLP-A LN: z0=ln2(ln1(x3)), z1..12=ln2(head4), z13=ln2(resid)
__global__ __launch_bounds__(64) void k_lnA(const float* __restrict__ resid,
                                            const float* __restrict__ x3,
                                            const float* __restrict__ tmp24,
                                            u16* __restrict__ mlpAb,
                                            const float* __restrict__ l1g, const float* __restrict__ l1b,
                                            const float* __restrict__ l2g, const float* __restrict__ l2b) {
    int row = blockIdx.x;            // 14*SS rows
    int z = row >> 7, s = row & 127;
    int lane = threadIdx.x;
    const float* src;
    if (z == 0) src = x3 + (size_t)s * DD;
    else if (z == 13) src = resid + (size_t)s * DD;
    else src = tmp24 + (size_t)(11 + z) * SD + (size_t)s * DD;
    float vals[12];
#pragma unroll
    for (int i = 0; i < 12; i++) vals[i] = src[lane + 64 * i];
    if (z == 0) wave_ln(vals, lane, l1g, l1b);
    wave_ln(vals, lane, l2g, l2b);
    u16* o = mlpAb + (size_t)z * SD + (size_t)s * DD;
#pragma unroll
    for (int i = 0; i < 12; i++) o[lane + 64 * i] = f2bf(vals[i]);
}

// ---------------- bf16 MFMA GEMM: C[z] = A[z] @ BT[z%zMod]^T (+bias if z>=biasLo), M=128
__global__ __launch_bounds__(256) void k_mm(
    const u16* __restrict__ A, const u16* __restrict__ BT,
    const float* __restrict__ bias, void* __restrict__ Cv,
    int N, int K, int lda, int ldbt, int ldc,
    long long sA, long long sBT, long long sC, long long sBias,
    int zMod, int biasLo, int mode) {
    __shared__ u16 As[128][40];
    __shared__ u16 Bs[64][40];
    int z = blockIdx.z;
    int zb = z % zMod;
    const u16* Ab = A + (size_t)z * sA;
    const u16* Bb = BT + (size_t)zb * sBT;
    int n0 = blockIdx.x * 64;
    int tid = threadIdx.x;
    int lane = tid & 63, wid = tid >> 6;
    int wm = (wid >> 1) * 64, wn = (wid & 1) * 32;
    int l15 = lane & 15, l4 = lane >> 4;
    int sr = tid >> 2, sseg = tid & 3;
    f32x4 acc[4][2];
#pragma unroll
    for (int i = 0; i < 4; i++) { acc[i][0] = (f32x4)0.f; acc[i][1] = (f32x4)0.f; }
    for (int k0 = 0; k0 < K; k0 += 32) {
        uint4 a0 = *(const uint4*)(Ab + (size_t)sr * lda + k0 + sseg * 8);
        uint4 a1 = *(const uint4*)(Ab + (size_t)(sr + 64) * lda + k0 + sseg * 8);
        uint4 bv = {0u, 0u, 0u, 0u};
        int n = n0 + sr;
        if (n < N) bv = *(const uint4*)(Bb + (size_t)n * ldbt + k0 + sseg * 8);
        *(uint4*)&As[sr][sseg * 8] = a0;
        *(uint4*)&As[sr + 64][sseg * 8] = a1;
        *(uint4*)&Bs[sr][sseg * 8] = bv;
        __syncthreads();
        short8 af[4], bfr[2];
#pragma unroll
        for (int i = 0; i < 4; i++) af[i] = *(const short8*)&As[wm + i * 16 + l15][l4 * 8];
#pragma unroll
        for (int j = 0; j < 2; j++) bfr[j] = *(const short8*)&Bs[wn + j * 16 + l15][l4 * 8];
#pragma unroll
        for (int i = 0; i < 4; i++)
#pragma unroll
            for (int j = 0; j < 2; j++)
                acc[i][j] = __builtin_amdgcn_mfma_f32_16x16x32_bf16(af[i], bfr[j], acc[i][j], 0, 0, 0);
        __syncthreads();
    }
    const float* bp = (bias != nullptr && z >= biasLo) ? bias + (size_t)zb * sBias : nullptr;
    if (mode == 0) {
        float* Cb = (float*)Cv + (size_t)z * sC;
#pragma unroll
        for (int i = 0; i < 4; i++) {
            int row = wm + i * 16 + l4 * 4;
#pragma unroll
            for (int j = 0; j < 2; j++) {
                int col = n0 + wn + j * 16 + l15;
                if (col >= N) continue;
                float bb = bp ? bp[col] : 0.f;
#pragma unroll
                for (int r = 0; r < 4; r++)
                    Cb[(size_t)(row + r) * ldc + col] = acc[i][j][r] + bb;
            }
        }
    } else {
        u16* Cb = (u16*)Cv + (size_t)z * sC;
#pragma unroll
        for (int i = 0; i < 4; i++) {
            int row = wm + i * 16 + l4 * 4;
#pragma unroll
            for (int j = 0; j < 2; j++) {
                int col = n0 + wn + j * 16 + l15;
                if (col >= N) continue;
                float bb = bp ? bp[col] : 0.f;
#pragma unroll
                for (int r = 0; r < 4; r++) {
                    float v = acc[i][j][r] + bb;
                    float c = v + 0.044715f * v * v * v;
                    float gv = 0.5f * v * (1.f + tanhf(0.7978845608028654f * c));
                    Cb[(size_t)(row + r) * ldc + col] = f2bf(gv);
                }
            }
        }
    }
}

// ---------------- fused causal attention on fused qkv [z][128][192] f32 -> ctx bf16
__global__ __launch_bounds__(256) void k_attn(const float* __restrict__ qkv,
                                              u16* __restrict__ ctx) {
    __shared__ float kv[SS * DHD];
    __shared__ float qs[16][DHD];
    __shared__ float sc[16][130];
    int z = blockIdx.y, s0 = blockIdx.x * 16;
    const float* base = qkv + (size_t)z * SS * 192;
    int tid = threadIdx.x;
    for (int idx = tid; idx < SS * DHD; idx += 256) {
        int t = idx >> 6, d = idx & 63;
        kv[idx] = base[t * 192 + 64 + d];
    }
    for (int idx = tid; idx < 16 * DHD; idx += 256) {
        int r = idx >> 6, d = idx & 63;
        qs[r][d] = base[(s0 + r) * 192 + d];
    }
    __syncthreads();
    int r = tid >> 4, tt = tid & 15;
    int s = s0 + r;
    float pl[8];
#pragma unroll
    for (int u = 0; u < 8; u++) {
        int t = tt + 16 * u;
        float dot;
        if (t <= s) {
            dot = 0.f;
            for (int d = 0; d < DHD; d++) dot += qs[r][d] * kv[t * DHD + d];
            dot *= 0.125f;
        } else {
            dot = -1e30f;
        }
        pl[u] = dot;
    }
    float mx = pl[0];
#pragma unroll
    for (int u = 1; u < 8; u++) mx = fmaxf(mx, pl[u]);
#pragma unroll
    for (int m = 1; m < 16; m <<= 1) mx = fmaxf(mx, __shfl_xor(mx, m, 16));
    float sum = 0.f;
#pragma unroll
    for (int u = 0; u < 8; u++) { pl[u] = __expf(pl[u] - mx); sum += pl[u]; }
#pragma unroll
    for (int m = 1; m < 16; m <<= 1) sum += __shfl_xor(sum, m, 16);
    float inv = 1.f / sum;
#pragma unroll
    for (int u = 0; u < 8; u++) sc[r][tt + 16 * u] = pl[u] * inv;
    __syncthreads();
    for (int idx = tid; idx < SS * DHD; idx += 256) {
        int t = idx >> 6, d = idx & 63;
        kv[idx] = base[t * 192 + 128 + d];
    }
    __syncthreads();
    int d = tid & 63, r0 = tid >> 6;
#pragma unroll
    for (int u = 0; u < 4; u++) {
        int rr = r0 + 4 * u;
        float a = 0.f;
        for (int t = 0; t < SS; t++) a += sc[rr][t] * kv[t * DHD + d];
        ctx[(size_t)z * SS * DHD + (size_t)(s0 + rr) * DHD + d] = f2bf(a);
    }
}

// ---------------- residual
__global__ void k_resid(const float* __restrict__ tmp, const float* __restrict__ proj_b_i,
                        const float* __restrict__ mproj_b_i, float* __restrict__ reci,
                        float* __restrict__ resid) {
    int sd = blockIdx.x * 256 + threadIdx.x;
    if (sd >= SD) return;
    int d = sd % DD;
    float a = reci[sd];
#pragma unroll
    for (int j = 0; j < 12; j++) {
        float v = tmp[(size_t)j * SD + sd];
        reci[(size_t)(1 + j) * SD + sd] = v;
        a += v;
    }
    resid[sd] = a + proj_b_i[d];
    reci[(size_t)27 * SD + sd] = mproj_b_i[d];
    reci[(size_t)28 * SD + sd] = proj_b_i[d];
}

// ---------------- c5 + new h (slot26 holds raw stream on entry)
__global__ void k_c5h(float* __restrict__ reci, const float* __restrict__ resid,
                      const float* __restrict__ mproj_b_i, float* __restrict__ h) {
    int sd = blockIdx.x * 256 + threadIdx.x;
    if (sd >= SD) return;
    int d = sd % DD;
    float s4 = 0.f;
#pragma unroll
    for (int j = 14; j <= 25; j++) s4 += reci[(size_t)j * SD + sd];
    float st = reci[(size_t)26 * SD + sd];
    reci[(size_t)26 * SD + sd] = st - reci[(size_t)13 * SD + sd] - s4;
    h[sd] = resid[sd] + st + mproj_b_i[d];
}

extern "C" void kernel_launch(void* const* d_in, const int* in_sizes, int n_in,
                              void* d_out, int out_size, void* d_ws, size_t ws_size,
                              hipStream_t stream) {
    const int* ids = (const int*)d_in[0];
    const int* rm = (const int*)d_in[2];
    const float* wte = (const float*)d_in[3];
    const float* wpe = (const float*)d_in[4];
    const float* qkv_w = (const float*)d_in[5];
    const float* qkv_b = (const float*)d_in[6];
    const float* proj_w = (const float*)d_in[7];
    const float* proj_b = (const float*)d_in[8];
    const float* ln1_g = (const float*)d_in[9];
    const float* ln1_b = (const float*)d_in[10];
    const float* ln2_g = (const float*)d_in[11];
    const float* ln2_b = (const float*)d_in[12];
    const float* fc_w = (const float*)d_in[13];
    const float* fc_b = (const float*)d_in[14];
    const float* mproj_w = (const float*)d_in[15];
    const float* mproj_b = (const float*)d_in[16];
    const float* lnf_g = (const float*)d_in[17];
    const float* lnf_b = (const float*)d_in[18];
    float* out = (float*)d_out;

    float* ws = (float*)d_ws;
    size_t off = 0;
    float* records = ws + off; off += (size_t)LL * NCC * SD;
    float* x24  = ws + off; off += (size_t)24 * SD;
    float* tmp24= ws + off; off += (size_t)24 * SD;
    float* h    = ws + off; off += SD;
    float* x3   = ws + off; off += SD;
    float* resid= ws + off; off += SD;
    float* qkvf = ws + off; off += (size_t)24 * SS * 192;
    float* qkvbp= ws + off; off += (size_t)LL * 3 * DD;
    u16* xlnb  = (u16*)(ws + off); off += (size_t)24 * SD / 2;
    u16* mlpAb = (u16*)(ws + off); off += (size_t)14 * SD / 2;
    u16* hfcb  = (u16*)(ws + off); off += (size_t)14 * SF / 2;
    u16* ctxb  = (u16*)(ws + off); off += (size_t)24 * SS * DHD / 2;
    u16* lnfb  = (u16*)(ws + off); off += SD / 2;
    u16* qkvhT = (u16*)(ws + off); off += (size_t)LL * 2304 * DD / 2;
    u16* fcT   = (u16*)(ws + off); off += (size_t)LL * FF * DD / 2;
    u16* mprojT= (u16*)(ws + off); off += (size_t)LL * DD * FF / 2;
    u16* projT = (u16*)(ws + off); off += (size_t)LL * DD * DD / 2;
    u16* wteb  = (u16*)(ws + off); off += (size_t)VV * DD / 2;
    unsigned* lmu = (unsigned*)(ws + off);

    k_masku<<<(LL * TMAX + 255) / 256, 256, 0, stream>>>(rm, lmu);
    k_embed<<<SD / 256, 256, 0, stream>>>(ids, wte, wpe, h);
    k_cvt<<<((VV * DD / 4) + 255) / 256, 256, 0, stream>>>(wte, wteb, VV * DD / 4);
    k_qkvb<<<(LL * 3 * DD + 255) / 256, 256, 0, stream>>>(qkv_b, qkvbp);
    k_wt<<<dim3(36, 12, 12), 256, 0, stream>>>(qkv_w, qkvhT, DD, 3 * DD, 1,
                                               (long long)DD * 3 * DD, (long long)2304 * DD);
    k_wt<<<dim3(48, 12, 12), 256, 0, stream>>>(fc_w, fcT, DD, FF, 0,
                                               (long long)DD * FF, (long long)FF * DD);
    k_wt<<<dim3(12, 48, 12), 256, 0, stream>>>(mproj_w, mprojT, FF, DD, 0,
                                               (long long)FF * DD, (long long)DD * FF);
    k_wt<<<dim3(12, 12, 12), 256, 0, stream>>>(proj_w, projT, DD, DD, 0,
                                               (long long)DD * DD, (long long)DD * DD);

    for (int i = 0; i < LL; i++) {
        float* reci = records + (size_t)i * NCC * SD;
        const float* l1g = ln1_g + i * DD; const float* l1b = ln1_b + i * DD;
        const float* l2g = ln2_g + i * DD; const float* l2b = ln2_b + i * DD;
        const u16* qkvhTi = qkvhT + (size_t)i * 2304 * DD;
        const u16* fcTi = fcT + (size_t)i * FF * DD;
        const u16* mprojTi = mprojT + (size_t)i * DD * FF;
        const u16* projTi = projT + (size_t)i * DD * DD;

        k_check<<<SD / 64, 256, 0, stream>>>(records, lmu, h, reci, x24, x3, i);

        k_ln<<<24 * SS, 64, 0, stream>>>(x24, nullptr, xlnb, l1g, l1b, 24 * SS);
        k_mm<<<dim3(3, 1, 24), 256, 0, stream>>>(
            xlnb, qkvhTi, qkvbp + (size_t)i * 3 * DD, qkvf,
            192, DD, DD, DD, 192, SD, (long long)192 * DD, (long long)SS * 192, 192, 12, 0, 0);
        k_attn<<<dim3(SS / 16, 24), 256, 0, stream>>>(qkvf, ctxb);
        k_mm<<<dim3(12, 1, 24), 256, 0, stream>>>(
            ctxb, projTi, nullptr, tmp24,
            DD, DHD, DHD, DD, DD, (long long)SS * DHD, 64, SD, 0, 12, 99, 0);
        k_resid<<<SD / 256, 256, 0, stream>>>(tmp24, proj_b + i * DD, mproj_b + i * DD, reci, resid);

        // mlpAb z: 0=ln2(ln1(x3)) [c3], 1..12=ln2(head4) [c4], 13=ln2(resid) [stream]
        k_lnA<<<14 * SS, 64, 0, stream>>>(resid, x3, tmp24, mlpAb, l1g, l1b, l2g, l2b);

        // fc batch 14, fused gelu->bf16; bias only z=13 (stream)
        k_mm<<<dim3(48, 1, 14), 256, 0, stream>>>(
            mlpAb, fcTi, fc_b + (size_t)i * FF, hfcb,
            FF, DD, DD, DD, FF, SD, 0, SF, 0, 1, 13, 1);
        // mproj batch 14 -> records slots 13..26 (z=13 -> slot26 = raw stream)
        k_mm<<<dim3(12, 1, 14), 256, 0, stream>>>(
            hfcb, mprojTi, nullptr, reci + (size_t)13 * SD,
            DD, FF, FF, FF, DD, SF, 0, SD, 0, 1, 99, 0);

        k_c5h<<<SD / 256, 256, 0, stream>>>(reci, resid, mproj_b + i * DD, h);
    }

    k_ln<<<SS, 64, 0, stream>>>(h, nullptr, lnfb, lnf_g, lnf_b, SS);
    k_mm<<<dim3((VV + 63) / 64, 1, 1), 256, 0, stream>>>(
        lnfb, wteb, nullptr, out,
        VV, DD, DD, DD, VV, 0, 0, 0, 0, 1, 99, 0);
}